// Round 10
// baseline (787.392 us; speedup 1.0000x reference)
//
#include <hip/hip_runtime.h>
#include <hip/hip_bf16.h>
#include <math.h>

// Problem constants (B=2, S=2048, D=1024, H=2816, E=8, top-2)
// R9: HOLD #4 of the audited kernel (10th straight GPU timeout; no
// measurement has ever landed). Blind structural edits remain negative-EV
// vs. a correctness loss on a possibly-single-shot bench.
#define B_ 2
#define S_ 2048
#define D_ 1024
#define H_ 2816
#define E_ 8
#define T_ 4096   // B_*S_

typedef unsigned short ushort_t;
typedef __attribute__((ext_vector_type(4))) short bf16x4;
typedef __attribute__((ext_vector_type(8))) short bf16x8;
typedef __attribute__((ext_vector_type(4))) float f32x4;

// fp32 -> bf16 RNE via compiler's native conversion
__device__ __forceinline__ ushort_t f2bf(float f) {
    __hip_bfloat16 h = __float2bfloat16(f);
    return *(ushort_t*)&h;
}

// 8-element LDS store/load as two aligned 8B halves (KP=40 rows are only
// 8B-aligned; b128 would be misaligned on odd rows). b64 and b128 have
// equal LDS bytes/cycle (m134), and KP=40 (20-bank row stride) gives
// 2-way aliasing (free, m136) vs 4-way for KP=48 — layout is optimal.
__device__ __forceinline__ void st8(ushort_t* p, const ushort_t* v) {
    bf16x4 a = {(short)v[0], (short)v[1], (short)v[2], (short)v[3]};
    bf16x4 b = {(short)v[4], (short)v[5], (short)v[6], (short)v[7]};
    *(bf16x4*)p = a;
    *(bf16x4*)(p + 4) = b;
}
__device__ __forceinline__ void st8v(ushort_t* p, bf16x8 v) {
    bf16x4 a = __builtin_shufflevector(v, v, 0, 1, 2, 3);
    bf16x4 b = __builtin_shufflevector(v, v, 4, 5, 6, 7);
    *(bf16x4*)p = a;
    *(bf16x4*)(p + 4) = b;
}
__device__ __forceinline__ bf16x8 ld8(const ushort_t* p) {
    bf16x4 a = *(const bf16x4*)p;
    bf16x4 b = *(const bf16x4*)(p + 4);
    return __builtin_shufflevector(a, b, 0, 1, 2, 3, 4, 5, 6, 7);
}

// ---------------- workspace layout (bytes) ----------------
// [0, ~400KB)  router scratch (float/int views, see kernel_launch)
// HG  : bf16 [8192][2816]   packed per-expert hidden-gate rows
// XG  : bf16 [8192][1024]   packed per-expert gathered x rows (Tier A)
// W1T/W3T : bf16 [E][H][D]  transposed weights (K=D contiguous)  (Tier A)
// W2T     : bf16 [E][D][H]  transposed weights (K=H contiguous)  (Tier A)
#define HG_OFF   524288ull
#define HG_BYTES 46137344ull                    // 8192*2816*2
#define XG_OFF   (HG_OFF + HG_BYTES)            // 46,661,632
#define XG_BYTES 16777216ull                    // 8192*1024*2
#define W1T_OFF  (XG_OFF + XG_BYTES)            // 63,438,848
#define WB_BYTES 46137344ull                    // 8*1024*2816*2
#define W3T_OFF  (W1T_OFF + WB_BYTES)           // 109,576,192
#define W2T_OFF  (W3T_OFF + WB_BYTES)           // 155,713,536
#define TIER_A_NEED (W2T_OFF + WB_BYTES)        // 201,850,880
#define TIER_B_NEED (HG_OFF + HG_BYTES)         //  46,661,632

// ============================ router (fp32-exact) ============================

__global__ __launch_bounds__(64) void router_logits_k(
    const float* __restrict__ x, const float* __restrict__ rw,
    const float* __restrict__ rb, float* __restrict__ logits)
{
    const int t = blockIdx.x;
    const int lane = threadIdx.x;
    const float* xp = x + (size_t)t * D_;
    float acc[E_] = {0.f,0.f,0.f,0.f,0.f,0.f,0.f,0.f};
    #pragma unroll
    for (int i = 0; i < 4; ++i) {
        const int d = lane * 4 + i * 256;
        float4 xv = *(const float4*)&xp[d];
        #pragma unroll
        for (int dd = 0; dd < 4; ++dd) {
            const float xd = (&xv.x)[dd];
            float4 r0 = *(const float4*)&rw[(size_t)(d + dd) * E_];
            float4 r1 = *(const float4*)&rw[(size_t)(d + dd) * E_ + 4];
            acc[0] = fmaf(xd, r0.x, acc[0]);
            acc[1] = fmaf(xd, r0.y, acc[1]);
            acc[2] = fmaf(xd, r0.z, acc[2]);
            acc[3] = fmaf(xd, r0.w, acc[3]);
            acc[4] = fmaf(xd, r1.x, acc[4]);
            acc[5] = fmaf(xd, r1.y, acc[5]);
            acc[6] = fmaf(xd, r1.z, acc[6]);
            acc[7] = fmaf(xd, r1.w, acc[7]);
        }
    }
    #pragma unroll
    for (int e = 0; e < E_; ++e) {
        float v = acc[e];
        #pragma unroll
        for (int off = 32; off > 0; off >>= 1) v += __shfl_xor(v, off);
        acc[e] = v;
    }
    if (lane == 0) {
        #pragma unroll
        for (int e = 0; e < E_; ++e)
            logits[(size_t)t * E_ + e] = acc[e] + rb[e];
    }
}

// F.normalize(dim=1): per-(b,e) L2 norm over the SEQUENCE axis.
__global__ __launch_bounds__(256) void router_norms_k(
    const float* __restrict__ logits, float* __restrict__ nrm)
{
    const int be = blockIdx.x;          // b*E_+e
    const int b = be >> 3, e = be & 7;
    float s = 0.f;
    for (int i = threadIdx.x; i < S_; i += 256) {
        float v = logits[((size_t)b * S_ + i) * E_ + e];
        s = fmaf(v, v, s);
    }
    __shared__ float red[4];
    #pragma unroll
    for (int off = 32; off > 0; off >>= 1) s += __shfl_xor(s, off);
    if ((threadIdx.x & 63) == 0) red[threadIdx.x >> 6] = s;
    __syncthreads();
    if (threadIdx.x == 0) {
        float tot = red[0] + red[1] + red[2] + red[3];
        nrm[be] = fmaxf(sqrtf(tot), 1e-12f);
    }
}

__global__ __launch_bounds__(256) void router_softmax_top2_k(
    float* __restrict__ probs, const float* __restrict__ nrm,
    int* __restrict__ cnt, int* __restrict__ lists, float* __restrict__ wlist)
{
    const int t = blockIdx.x * 256 + threadIdx.x;
    if (t >= T_) return;
    const int b = t / S_;
    float l[E_];
    #pragma unroll
    for (int e = 0; e < E_; ++e)
        l[e] = probs[(size_t)t * E_ + e] / nrm[b * E_ + e];
    float m = l[0];
    #pragma unroll
    for (int e = 1; e < E_; ++e) m = fmaxf(m, l[e]);
    float sum = 0.f;
    #pragma unroll
    for (int e = 0; e < E_; ++e) { l[e] = expf(l[e] - m); sum += l[e]; }
    const float inv = 1.0f / sum;
    int i1 = 0; float p1 = -1.f;
    #pragma unroll
    for (int e = 0; e < E_; ++e) {
        l[e] *= inv;
        probs[(size_t)t * E_ + e] = l[e];
        if (l[e] > p1) { p1 = l[e]; i1 = e; }
    }
    int i2 = -1; float p2 = -1.f;
    #pragma unroll
    for (int e = 0; e < E_; ++e)
        if (e != i1 && l[e] > p2) { p2 = l[e]; i2 = e; }
    int pos1 = atomicAdd(&cnt[i1], 1);
    lists[i1 * T_ + pos1] = t; wlist[i1 * T_ + pos1] = p1;
    int pos2 = atomicAdd(&cnt[i2], 1);
    lists[i2 * T_ + pos2] = t; wlist[i2 * T_ + pos2] = p2;
}

__global__ __launch_bounds__(256) void aux_loss_k(
    const float* __restrict__ probs, float* __restrict__ out_aux)
{
    float s = 0.f;
    for (int i = threadIdx.x; i < S_ * E_; i += 256) {
        float avg = 0.5f * (probs[i] + probs[(size_t)S_ * E_ + i]);
        float d = 0.125f - avg;
        s = fmaf(d, d, s);
    }
    __shared__ float red[4];
    #pragma unroll
    for (int off = 32; off > 0; off >>= 1) s += __shfl_xor(s, off);
    if ((threadIdx.x & 63) == 0) red[threadIdx.x >> 6] = s;
    __syncthreads();
    if (threadIdx.x == 0)
        out_aux[0] = red[0] + red[1] + red[2] + red[3];
}

__global__ void offs_k(const int* __restrict__ cnt, int* __restrict__ offs)
{
    if (threadIdx.x == 0) {
        int s = 0;
        #pragma unroll
        for (int e = 0; e < E_; ++e) { offs[e] = s; s += cnt[e]; }
    }
}

// ==================== Tier-A pre-passes (bf16 hoist + transpose) ====================

// Per-expert transpose+convert: src fp32 [E][R][C] -> dst bf16 [E][C][R].
// Classic 32x32 LDS tile (fp32 [32][33]: conflict-free both directions).
// Block (32,8), each thread moves 4 elements.
__global__ __launch_bounds__(256) void transpose_bf16_k(
    const float* __restrict__ src, ushort_t* __restrict__ dst, int R, int C)
{
    __shared__ float tile[32][33];
    const int e = blockIdx.z;
    src += (size_t)e * R * C;
    dst += (size_t)e * R * C;
    const int c0 = blockIdx.x * 32, r0 = blockIdx.y * 32;
    const int tx = threadIdx.x, ty = threadIdx.y;
    #pragma unroll
    for (int k = 0; k < 4; ++k)
        tile[ty + k * 8][tx] = src[(size_t)(r0 + ty + k * 8) * C + c0 + tx];
    __syncthreads();
    #pragma unroll
    for (int k = 0; k < 4; ++k)
        dst[(size_t)(c0 + ty + k * 8) * R + r0 + tx] = f2bf(tile[tx][ty + k * 8]);
}

// gather routed token rows into packed bf16 XG[8192][1024]
__global__ __launch_bounds__(64) void gather_xg_k(
    const float* __restrict__ x, const int* __restrict__ offs,
    const int* __restrict__ lists, ushort_t* __restrict__ xg)
{
    const int p = blockIdx.x;           // packed row 0..8191
    int e = 0;
    #pragma unroll
    for (int k = 1; k < E_; ++k) if (p >= offs[k]) e = k;
    const int tok = lists[e * T_ + (p - offs[e])];
    const int lane = threadIdx.x;
    const float* src = x + (size_t)tok * D_ + lane * 16;
    float4 q0 = *(const float4*)src;
    float4 q1 = *(const float4*)(src + 4);
    float4 q2 = *(const float4*)(src + 8);
    float4 q3 = *(const float4*)(src + 12);
    bf16x8 o0 = {(short)f2bf(q0.x),(short)f2bf(q0.y),(short)f2bf(q0.z),(short)f2bf(q0.w),
                 (short)f2bf(q1.x),(short)f2bf(q1.y),(short)f2bf(q1.z),(short)f2bf(q1.w)};
    bf16x8 o1 = {(short)f2bf(q2.x),(short)f2bf(q2.y),(short)f2bf(q2.z),(short)f2bf(q2.w),
                 (short)f2bf(q3.x),(short)f2bf(q3.y),(short)f2bf(q3.z),(short)f2bf(q3.w)};
    ushort_t* dst = xg + (size_t)p * D_ + lane * 16;
    *(bf16x8*)dst = o0;
    *(bf16x8*)(dst + 8) = o1;
}

// ======================= MFMA two-pass FFN =======================
// Fragment conventions (learn_hip m89..m97 verified):
//   A (M16xK32): lane l holds A[l&15][(l>>4)*8+j]  (bf16x8)
//   B (K32xN16): lane l holds B[(l>>4)*8+j][l&15]  (bf16x8)
//   C/D:         lane l reg i -> D[(l>>4)*4+i][l&15]
// LDS: A [m][k], B transposed [n][k], k-stride KP=40 (80B rows: 20-bank
// stride -> frag reads 2-way = free; all LDS ops are 8B-aligned b64).
// Cycle model per block K-step (Tier A): MFMA 310 CU-cy vs LDS 156 cy vs
// staging ~1KB/wave global -> MFMA-bound with ~2x LDS margin.
// Grid: 1-D + XCD swizzle; nwg/8 = one expert's tile grid per XCD.

#define MT1 128   // tokens per tile
#define NT  64    // n-cols per tile
#define BK  32
#define KP  40

// ---------- Tier A pass 1: all-bf16, K-contiguous weights ----------
__global__ __launch_bounds__(256) void moe_pass1b(
    const ushort_t* __restrict__ xg,
    const ushort_t* __restrict__ w1t, const ushort_t* __restrict__ w3t,
    const int* __restrict__ cnt, const int* __restrict__ offs,
    ushort_t* __restrict__ hg)
{
    const int q = (int)gridDim.x >> 3;                  // 1408 per XCD
    const int wg = ((int)blockIdx.x & 7) * q + ((int)blockIdx.x >> 3);
    const int e = wg / ((T_ / MT1) * (H_ / NT));
    const int r = wg % ((T_ / MT1) * (H_ / NT));
    const int tile0 = (r & (T_ / MT1 - 1)) * MT1;       // tile fastest
    const int hc = (r / (T_ / MT1)) * NT;

    const int ne = cnt[e];
    if (tile0 >= ne) return;
    const int base = offs[e];

    __shared__ __align__(16) ushort_t Xs[MT1][KP];
    __shared__ __align__(16) ushort_t W1s[NT][KP];
    __shared__ __align__(16) ushort_t W3s[NT][KP];

    const int tid = threadIdx.x;
    const int lane = tid & 63;
    const int l15 = lane & 15, lk = (lane >> 4) * 8;
    const int n0 = (tid >> 6) * 16;      // wave's n-strip

    f32x4 acc1[8], acc3[8];
    #pragma unroll
    for (int m = 0; m < 8; ++m) {
        acc1[m] = (f32x4){0.f,0.f,0.f,0.f};
        acc3[m] = (f32x4){0.f,0.f,0.f,0.f};
    }

    const int sm  = tid >> 1;            // X stage: tile row 0..127
    const int skp = (tid & 1) * 16;      // X stage: k part (16 elems)
    const int sn  = tid & 63;            // W stage: n col
    const int swk = (tid >> 6) * 8;      // W stage: k part (8 elems)
    // packed A row (clamped for the partial tail tile)
    const int srow = base + ((tile0 + sm < ne) ? tile0 + sm : ne - 1);
    const ushort_t* xrow = xg + (size_t)srow * D_ + skp;
    // transposed weights: row = n (h), K contiguous -> one dwordx4 per step
    const ushort_t* W1p = w1t + ((size_t)e * H_ + hc + sn) * D_ + swk;
    const ushort_t* W3p = w3t + ((size_t)e * H_ + hc + sn) * D_ + swk;

    for (int k0 = 0; k0 < D_; k0 += BK) {
        // issue this step's global loads before the barrier: overlaps the
        // prior iteration's MFMA + LDS drain (T14-lite)
        bf16x8 x0 = *(const bf16x8*)(xrow + k0);
        bf16x8 x1 = *(const bf16x8*)(xrow + k0 + 8);
        bf16x8 w1v = *(const bf16x8*)(W1p + k0);
        bf16x8 w3v = *(const bf16x8*)(W3p + k0);
        __syncthreads();   // prior iteration's frag reads complete
        st8v(&Xs[sm][skp], x0);
        st8v(&Xs[sm][skp + 8], x1);
        st8v(&W1s[sn][swk], w1v);
        st8v(&W3s[sn][swk], w3v);
        __syncthreads();
        bf16x8 bf1 = ld8(&W1s[n0 + l15][lk]);
        bf16x8 bf3 = ld8(&W3s[n0 + l15][lk]);
        #pragma unroll
        for (int m = 0; m < 8; ++m) {
            bf16x8 af = ld8(&Xs[m * 16 + l15][lk]);
            acc1[m] = __builtin_amdgcn_mfma_f32_16x16x32_bf16(af, bf1, acc1[m], 0, 0, 0);
            acc3[m] = __builtin_amdgcn_mfma_f32_16x16x32_bf16(af, bf3, acc3[m], 0, 0, 0);
        }
    }

    // epilogue: hg = sin(s1)*s3 -> bf16 (HW v_sin; err ~1e-6 << bf16 quant)
    const int rbase = (lane >> 4) * 4;
    const int hcol = hc + n0 + l15;
    #pragma unroll
    for (int m = 0; m < 8; ++m) {
        #pragma unroll
        for (int i = 0; i < 4; ++i) {
            int rr = tile0 + m * 16 + rbase + i;
            if (rr < ne) {
                float v = __sinf(acc1[m][i]) * acc3[m][i];
                hg[((size_t)base + rr) * H_ + hcol] = f2bf(v);
            }
        }
    }
}

// ---------- Tier A pass 2: K-contiguous W2T, fp32 atomic scatter ----------
__global__ __launch_bounds__(256) void moe_pass2b(
    const ushort_t* __restrict__ hg, const ushort_t* __restrict__ w2t,
    const int* __restrict__ cnt, const int* __restrict__ offs,
    const int* __restrict__ lists, const float* __restrict__ wlist,
    float* __restrict__ out)
{
    const int q = (int)gridDim.x >> 3;                  // 512 per XCD
    const int wg = ((int)blockIdx.x & 7) * q + ((int)blockIdx.x >> 3);
    const int e = wg / ((T_ / MT1) * (D_ / NT));
    const int r = wg % ((T_ / MT1) * (D_ / NT));
    const int tile0 = (r & (T_ / MT1 - 1)) * MT1;
    const int nc = (r / (T_ / MT1)) * NT;

    const int ne = cnt[e];
    if (tile0 >= ne) return;

    __shared__ __align__(16) ushort_t As[MT1][KP];
    __shared__ __align__(16) ushort_t Bs[NT][KP];
    __shared__ int   toks[MT1];
    __shared__ float wts[MT1];

    const int tid = threadIdx.x;
    if (tid < MT1) {
        int i = tile0 + tid;
        if (i < ne) { toks[tid] = lists[e * T_ + i]; wts[tid] = wlist[e * T_ + i]; }
        else        { toks[tid] = lists[e * T_ + (ne - 1)]; wts[tid] = 0.f; }
    }
    __syncthreads();

    const int lane = tid & 63;
    const int l15 = lane & 15, lk = (lane >> 4) * 8;
    const int n0 = (tid >> 6) * 16;

    f32x4 acc[8];
    #pragma unroll
    for (int m = 0; m < 8; ++m) acc[m] = (f32x4){0.f,0.f,0.f,0.f};

    const int sm  = tid >> 1;
    const int skp = (tid & 1) * 16;
    const int sn  = tid & 63;
    const int swk = (tid >> 6) * 8;
    const int mrow = (tile0 + sm < ne) ? tile0 + sm : ne - 1;
    const size_t arow = ((size_t)offs[e] + mrow) * H_;
    // transposed W2: row = n (d), K=h contiguous
    const ushort_t* W2p = w2t + ((size_t)e * D_ + nc + sn) * H_ + swk;

    for (int k0 = 0; k0 < H_; k0 += BK) {
        bf16x8 a0 = *(const bf16x8*)&hg[arow + k0 + skp];
        bf16x8 a1 = *(const bf16x8*)&hg[arow + k0 + skp + 8];
        bf16x8 b8 = *(const bf16x8*)(W2p + k0);
        __syncthreads();
        st8v(&As[sm][skp], a0);
        st8v(&As[sm][skp + 8], a1);
        st8v(&Bs[sn][swk], b8);
        __syncthreads();
        bf16x8 bf = ld8(&Bs[n0 + l15][lk]);
        #pragma unroll
        for (int m = 0; m < 8; ++m) {
            bf16x8 af = ld8(&As[m * 16 + l15][lk]);
            acc[m] = __builtin_amdgcn_mfma_f32_16x16x32_bf16(af, bf, acc[m], 0, 0, 0);
        }
    }

    const int rbase = (lane >> 4) * 4;
    const int dcol = nc + n0 + l15;
    #pragma unroll
    for (int m = 0; m < 8; ++m) {
        #pragma unroll
        for (int i = 0; i < 4; ++i) {
            int tloc = m * 16 + rbase + i;
            if (tile0 + tloc < ne)
                atomicAdd(&out[(size_t)toks[tloc] * D_ + dcol], acc[m][i] * wts[tloc]);
        }
    }
}

// ---------- Tier B pass 1/2: in-loop cvt (audited round-3 path) ----------
__global__ __launch_bounds__(256) void moe_pass1(
    const float* __restrict__ x,
    const float* __restrict__ w1, const float* __restrict__ w3,
    const int* __restrict__ cnt, const int* __restrict__ offs,
    const int* __restrict__ lists, ushort_t* __restrict__ hg)
{
    const int q = (int)gridDim.x >> 3;
    const int wg = ((int)blockIdx.x & 7) * q + ((int)blockIdx.x >> 3);
    const int e = wg / ((T_ / MT1) * (H_ / NT));
    const int r = wg % ((T_ / MT1) * (H_ / NT));
    const int tile0 = (r & (T_ / MT1 - 1)) * MT1;
    const int hc = (r / (T_ / MT1)) * NT;

    const int ne = cnt[e];
    if (tile0 >= ne) return;

    __shared__ __align__(16) ushort_t Xs[MT1][KP];
    __shared__ __align__(16) ushort_t W1s[NT][KP];
    __shared__ __align__(16) ushort_t W3s[NT][KP];
    __shared__ int toks[MT1];

    const int tid = threadIdx.x;
    if (tid < MT1) {
        int i = tile0 + tid;
        toks[tid] = lists[e * T_ + (i < ne ? i : ne - 1)];
    }
    __syncthreads();

    const float* W1e = w1 + (size_t)e * D_ * H_;
    const float* W3e = w3 + (size_t)e * D_ * H_;

    const int lane = tid & 63;
    const int l15 = lane & 15, lk = (lane >> 4) * 8;
    const int n0 = (tid >> 6) * 16;

    f32x4 acc1[8], acc3[8];
    #pragma unroll
    for (int m = 0; m < 8; ++m) {
        acc1[m] = (f32x4){0.f,0.f,0.f,0.f};
        acc3[m] = (f32x4){0.f,0.f,0.f,0.f};
    }

    const int sm  = tid >> 1;
    const int skp = (tid & 1) * 16;
    const int sn  = tid & 63;
    const int swk = (tid >> 6) * 8;
    const int xtok = toks[sm];

    for (int k0 = 0; k0 < D_; k0 += BK) {
        const float* xr = x + (size_t)xtok * D_ + k0 + skp;
        float4 xq0 = *(const float4*)xr;
        float4 xq1 = *(const float4*)(xr + 4);
        float4 xq2 = *(const float4*)(xr + 8);
        float4 xq3 = *(const float4*)(xr + 12);
        ushort_t xv[16] = {
            f2bf(xq0.x), f2bf(xq0.y), f2bf(xq0.z), f2bf(xq0.w),
            f2bf(xq1.x), f2bf(xq1.y), f2bf(xq1.z), f2bf(xq1.w),
            f2bf(xq2.x), f2bf(xq2.y), f2bf(xq2.z), f2bf(xq2.w),
            f2bf(xq3.x), f2bf(xq3.y), f2bf(xq3.z), f2bf(xq3.w)};
        ushort_t w1v[8], w3v[8];
        #pragma unroll
        for (int j = 0; j < 8; ++j) {
            w1v[j] = f2bf(W1e[(size_t)(k0 + swk + j) * H_ + hc + sn]);
            w3v[j] = f2bf(W3e[(size_t)(k0 + swk + j) * H_ + hc + sn]);
        }
        __syncthreads();
        st8(&Xs[sm][skp], xv);
        st8(&Xs[sm][skp + 8], xv + 8);
        st8(&W1s[sn][swk], w1v);
        st8(&W3s[sn][swk], w3v);
        __syncthreads();
        bf16x8 bf1 = ld8(&W1s[n0 + l15][lk]);
        bf16x8 bf3 = ld8(&W3s[n0 + l15][lk]);
        #pragma unroll
        for (int m = 0; m < 8; ++m) {
            bf16x8 af = ld8(&Xs[m * 16 + l15][lk]);
            acc1[m] = __builtin_amdgcn_mfma_f32_16x16x32_bf16(af, bf1, acc1[m], 0, 0, 0);
            acc3[m] = __builtin_amdgcn_mfma_f32_16x16x32_bf16(af, bf3, acc3[m], 0, 0, 0);
        }
    }

    const int rbase = (lane >> 4) * 4;
    const int hcol = hc + n0 + l15;
    const size_t hgbase = (size_t)offs[e];
    #pragma unroll
    for (int m = 0; m < 8; ++m) {
        #pragma unroll
        for (int i = 0; i < 4; ++i) {
            int rr = tile0 + m * 16 + rbase + i;
            if (rr < ne) {
                float v = __sinf(acc1[m][i]) * acc3[m][i];
                hg[(hgbase + rr) * H_ + hcol] = f2bf(v);
            }
        }
    }
}

__global__ __launch_bounds__(256) void moe_pass2(
    const ushort_t* __restrict__ hg, const float* __restrict__ w2,
    const int* __restrict__ cnt, const int* __restrict__ offs,
    const int* __restrict__ lists, const float* __restrict__ wlist,
    float* __restrict__ out)
{
    const int q = (int)gridDim.x >> 3;
    const int wg = ((int)blockIdx.x & 7) * q + ((int)blockIdx.x >> 3);
    const int e = wg / ((T_ / MT1) * (D_ / NT));
    const int r = wg % ((T_ / MT1) * (D_ / NT));
    const int tile0 = (r & (T_ / MT1 - 1)) * MT1;
    const int nc = (r / (T_ / MT1)) * NT;

    const int ne = cnt[e];
    if (tile0 >= ne) return;

    __shared__ __align__(16) ushort_t As[MT1][KP];
    __shared__ __align__(16) ushort_t Bs[NT][KP];
    __shared__ int   toks[MT1];
    __shared__ float wts[MT1];

    const int tid = threadIdx.x;
    if (tid < MT1) {
        int i = tile0 + tid;
        if (i < ne) { toks[tid] = lists[e * T_ + i]; wts[tid] = wlist[e * T_ + i]; }
        else        { toks[tid] = lists[e * T_ + (ne - 1)]; wts[tid] = 0.f; }
    }
    __syncthreads();

    const float* W2e = w2 + (size_t)e * H_ * D_;

    const int lane = tid & 63;
    const int l15 = lane & 15, lk = (lane >> 4) * 8;
    const int n0 = (tid >> 6) * 16;

    f32x4 acc[8];
    #pragma unroll
    for (int m = 0; m < 8; ++m) acc[m] = (f32x4){0.f,0.f,0.f,0.f};

    const int sm  = tid >> 1;
    const int skp = (tid & 1) * 16;
    const int sn  = tid & 63;
    const int swk = (tid >> 6) * 8;
    const int mrow = (tile0 + sm < ne) ? tile0 + sm : ne - 1;
    const size_t arow = ((size_t)offs[e] + mrow) * H_;

    for (int k0 = 0; k0 < H_; k0 += BK) {
        bf16x8 a0 = *(const bf16x8*)&hg[arow + k0 + skp];
        bf16x8 a1 = *(const bf16x8*)&hg[arow + k0 + skp + 8];
        ushort_t b8[8];
        #pragma unroll
        for (int j = 0; j < 8; ++j)
            b8[j] = f2bf(W2e[(size_t)(k0 + swk + j) * D_ + nc + sn]);
        __syncthreads();
        st8v(&As[sm][skp], a0);
        st8v(&As[sm][skp + 8], a1);
        st8(&Bs[sn][swk], b8);
        __syncthreads();
        bf16x8 bf = ld8(&Bs[n0 + l15][lk]);
        #pragma unroll
        for (int m = 0; m < 8; ++m) {
            bf16x8 af = ld8(&As[m * 16 + l15][lk]);
            acc[m] = __builtin_amdgcn_mfma_f32_16x16x32_bf16(af, bf, acc[m], 0, 0, 0);
        }
    }

    const int rbase = (lane >> 4) * 4;
    const int dcol = nc + n0 + l15;
    #pragma unroll
    for (int m = 0; m < 8; ++m) {
        #pragma unroll
        for (int i = 0; i < 4; ++i) {
            int tloc = m * 16 + rbase + i;
            if (tile0 + tloc < ne)
                atomicAdd(&out[(size_t)toks[tloc] * D_ + dcol], acc[m][i] * wts[tloc]);
        }
    }
}

// ================= fallback fused fp32 FFN (small ws) =================
#define TMF 8
#define HCF 256

__global__ __launch_bounds__(256) void ffn_f32_k(
    const float* __restrict__ x,
    const float* __restrict__ w1, const float* __restrict__ w2,
    const float* __restrict__ w3,
    const int* __restrict__ cnt, const int* __restrict__ lists,
    const float* __restrict__ wlist, float* __restrict__ out)
{
    const int e = blockIdx.y;
    const int ne = cnt[e];
    const int tile0 = blockIdx.x * TMF;
    if (tile0 >= ne) return;

    __shared__ __align__(16) float xs[TMF][D_];
    __shared__ __align__(16) float hgs[TMF][HCF];
    __shared__ int   toks[TMF];
    __shared__ float wts[TMF];

    const int tid = threadIdx.x;
    if (tid < TMF) {
        int i = tile0 + tid;
        if (i < ne) { toks[tid] = lists[e * T_ + i]; wts[tid] = wlist[e * T_ + i]; }
        else        { toks[tid] = lists[e * T_ + tile0]; wts[tid] = 0.f; }
    }
    __syncthreads();

    for (int slot = tid; slot < TMF * (D_ / 4); slot += 256) {
        int j = slot >> 8, dq = slot & 255;
        *(float4*)&xs[j][dq * 4] = *(const float4*)&x[(size_t)toks[j] * D_ + dq * 4];
    }

    const float* W1 = w1 + (size_t)e * D_ * H_;
    const float* W3 = w3 + (size_t)e * D_ * H_;
    const float* W2 = w2 + (size_t)e * H_ * D_;

    float acc[TMF][4];
    #pragma unroll
    for (int j = 0; j < TMF; ++j)
        #pragma unroll
        for (int c = 0; c < 4; ++c) acc[j][c] = 0.f;

    for (int hcb = 0; hcb < H_; hcb += HCF) {
        const int h = hcb + tid;
        float a[TMF], b[TMF];
        #pragma unroll
        for (int j = 0; j < TMF; ++j) { a[j] = 0.f; b[j] = 0.f; }
        for (int d4 = 0; d4 < D_ / 4; ++d4) {
            const int d = d4 * 4;
            float4 xv[TMF];
            #pragma unroll
            for (int j = 0; j < TMF; ++j) xv[j] = *(const float4*)&xs[j][d];
            #pragma unroll
            for (int dd = 0; dd < 4; ++dd) {
                float w1v = W1[(size_t)(d + dd) * H_ + h];
                float w3v = W3[(size_t)(d + dd) * H_ + h];
                #pragma unroll
                for (int j = 0; j < TMF; ++j) {
                    float xj = (&xv[j].x)[dd];
                    a[j] = fmaf(xj, w1v, a[j]);
                    b[j] = fmaf(xj, w3v, b[j]);
                }
            }
        }
        __syncthreads();
        #pragma unroll
        for (int j = 0; j < TMF; ++j) hgs[j][tid] = __sinf(a[j]) * b[j];
        __syncthreads();
        for (int h4 = 0; h4 < HCF / 4; ++h4) {
            const int hh = h4 * 4;
            float4 hgv[TMF];
            #pragma unroll
            for (int j = 0; j < TMF; ++j) hgv[j] = *(const float4*)&hgs[j][hh];
            #pragma unroll
            for (int k = 0; k < 4; ++k) {
                #pragma unroll
                for (int c = 0; c < 4; ++c) {
                    const int d = tid + c * 256;
                    float w2v = W2[(size_t)(hcb + hh + k) * D_ + d];
                    #pragma unroll
                    for (int j = 0; j < TMF; ++j)
                        acc[j][c] = fmaf((&hgv[j].x)[k], w2v, acc[j][c]);
                }
            }
        }
        __syncthreads();
    }

    #pragma unroll
    for (int j = 0; j < TMF; ++j) {
        const float wt = wts[j];
        const int t = toks[j];
        #pragma unroll
        for (int c = 0; c < 4; ++c)
            atomicAdd(&out[(size_t)t * D_ + tid + c * 256], acc[j][c] * wt);
    }
}

// ============================ launch ============================

extern "C" void kernel_launch(void* const* d_in, const int* in_sizes, int n_in,
                              void* d_out, int out_size, void* d_ws, size_t ws_size,
                              hipStream_t stream) {
    const float* x  = (const float*)d_in[0];
    const float* w1 = (const float*)d_in[1];
    const float* w2 = (const float*)d_in[2];
    const float* w3 = (const float*)d_in[3];
    const float* rw = (const float*)d_in[4];
    const float* rb = (const float*)d_in[5];
    float* out = (float*)d_out;

    float* wsf   = (float*)d_ws;
    float* probs = wsf;                    // T_*E_
    float* nrm   = wsf + 32768;            // B_*E_
    int*   cnt   = (int*)(wsf + 32800);    // E_
    int*   lists = (int*)(wsf + 32832);    // E_*T_
    float* wlist = wsf + 65600;            // E_*T_
    int*   offs  = (int*)(wsf + 98368);    // E_
    ushort_t* hgbuf = (ushort_t*)((char*)d_ws + HG_OFF);
    ushort_t* xgbuf = (ushort_t*)((char*)d_ws + XG_OFF);
    ushort_t* w1t   = (ushort_t*)((char*)d_ws + W1T_OFF);
    ushort_t* w3t   = (ushort_t*)((char*)d_ws + W3T_OFF);
    ushort_t* w2t   = (ushort_t*)((char*)d_ws + W2T_OFF);

    hipMemsetAsync(d_out, 0, (size_t)T_ * D_ * sizeof(float), stream);
    hipMemsetAsync(cnt, 0, E_ * sizeof(int), stream);

    router_logits_k<<<T_, 64, 0, stream>>>(x, rw, rb, probs);
    router_norms_k<<<B_ * E_, 256, 0, stream>>>(probs, nrm);
    router_softmax_top2_k<<<T_ / 256, 256, 0, stream>>>(probs, nrm, cnt, lists, wlist);
    aux_loss_k<<<1, 256, 0, stream>>>(probs, out + (size_t)T_ * D_);

    if (ws_size >= TIER_A_NEED) {
        // w1,w3: [D][H] -> [H][D]; w2: [H][D] -> [D][H]  (per expert)
        transpose_bf16_k<<<dim3(H_ / 32, D_ / 32, E_), dim3(32, 8), 0, stream>>>(
            w1, w1t, D_, H_);
        transpose_bf16_k<<<dim3(H_ / 32, D_ / 32, E_), dim3(32, 8), 0, stream>>>(
            w3, w3t, D_, H_);
        transpose_bf16_k<<<dim3(D_ / 32, H_ / 32, E_), dim3(32, 8), 0, stream>>>(
            w2, w2t, H_, D_);
        offs_k<<<1, 64, 0, stream>>>(cnt, offs);
        gather_xg_k<<<2 * T_, 64, 0, stream>>>(x, offs, lists, xgbuf);
        moe_pass1b<<<8 * (T_ / MT1) * (H_ / NT), 256, 0, stream>>>(
            xgbuf, w1t, w3t, cnt, offs, hgbuf);
        moe_pass2b<<<8 * (T_ / MT1) * (D_ / NT), 256, 0, stream>>>(
            hgbuf, w2t, cnt, offs, lists, wlist, out);
    } else if (ws_size >= TIER_B_NEED) {
        offs_k<<<1, 64, 0, stream>>>(cnt, offs);
        moe_pass1<<<8 * (T_ / MT1) * (H_ / NT), 256, 0, stream>>>(
            x, w1, w3, cnt, offs, lists, hgbuf);
        moe_pass2<<<8 * (T_ / MT1) * (D_ / NT), 256, 0, stream>>>(
            hgbuf, w2, cnt, offs, lists, wlist, out);
    } else {
        ffn_f32_k<<<dim3(T_ / TMF, E_), 256, 0, stream>>>(
            x, w1, w2, w3, cnt, lists, wlist, out);
    }
}